// Round 8
// baseline (2162.169 us; speedup 1.0000x reference)
//
#include <hip/hip_runtime.h>

// Problem constants
#define Bn   64
#define Tn   512
#define Dn   256
#define Un   512
#define Mn   64
#define NTHR 256
#define GRID 128                  // 4 b-tiles x 32 u-tiles (e fused into every wg)

// ws layout (float index):
//   [0..127]     (zeroed; reserved)
//   HB_OFF  (65536 f)  hbuf as u64[2][64][256]: [tag32 | 2x bf16 h], double buffer
//   BP_OFF  ushort area: BPU (1572864 sh) gate weights, BPE (49152 sh) e weights
//   XF_OFF  uint4 area: x pre-converted to bf16 MFMA A-frag layout
//           XF[((bt*512 + t)*8 + kb)*64 + lane] = 8 bf16 = x[bt*16+(lane&15)][k=kb*32+(lane>>4)*8 + 0..7]
#define HB_OFF    5120
#define BP_OFF    70656
#define BPU_SH    1572864
#define BPE_SH    49152
#define XF_OFF    881664          // floats = BP_OFF + (BPU_SH+BPE_SH)/2
#define XF_U4     1048576         // 4*512*8*64 uint4 entries (16 MB)
#define WS_NEED_F (XF_OFF + XF_U4*4)

typedef __attribute__((ext_vector_type(8))) short short8;
typedef __attribute__((ext_vector_type(4))) float f32x4;
typedef unsigned long long ull;

union frag8 { short8 s; f32x4 f; uint4 u; };   // views for asm keep-alive / loads

__device__ __forceinline__ float sigmoidf_(float v) { return 1.0f / (1.0f + __expf(-v)); }
__device__ __forceinline__ float tanhf_(float v) {   // hw-exp tanh; |v| small here
    const float e = __expf(2.0f * v);
    return (e - 1.0f) / (e + 1.0f);
}

__device__ __forceinline__ unsigned short f2bf(float f) {   // RNE fp32 -> bf16
    unsigned u = __float_as_uint(f);
    return (unsigned short)((u + 0x7FFFu + ((u >> 16) & 1u)) >> 16);
}

__device__ __forceinline__ void st_agent_u64(ull* p, ull v) {
    __hip_atomic_store(p, v, __ATOMIC_RELAXED, __HIP_MEMORY_SCOPE_AGENT);
}
__device__ __forceinline__ ull ld_agent_u64(const void* p) {
    return __hip_atomic_load((const ull*)p, __ATOMIC_RELAXED, __HIP_MEMORY_SCOPE_AGENT);
}

template<bool USEXF>
__global__ __launch_bounds__(NTHR, 1) void xlstm_k(
    const float* __restrict__ x,
    const float* __restrict__ bi, const float* __restrict__ bf_,
    const float* __restrict__ bo, const float* __restrict__ bc,
    const float* __restrict__ be,
    float* __restrict__ out, float* __restrict__ ws)
{
    __shared__ unsigned short sA[16 * 776];  // 24.8 KB xh tile bf16 (row pad 8); x region only used by fallback
    __shared__ float zs[1024];               // gate z, swizzled: zs[row*4 + ((gate + row>>2)&3)]
    __shared__ float zel[16 * 68];           // ze [16 b][64 e] (pad 68)
    __shared__ float esm[16 * 68];           // e [16 b][64], DIRECT slot order
    __shared__ float sbe[64];                // be staged

    ull* hb64 = (ull*)(ws + HB_OFF);
    const unsigned short* BPU = (const unsigned short*)(ws + BP_OFF);
    const unsigned short* BPE = BPU + BPU_SH;
    const uint4* XFp = (const uint4*)(ws + XF_OFF);

    const int tid = threadIdx.x, wg = blockIdx.x;
    const int bt = wg >> 5, r = wg & 31;
    const int b0 = bt << 4, u0 = r << 4;
    const int lane = tid & 63, w = tid >> 6;       // wave = gate index
    const int quad = lane >> 4, m16 = lane & 15;
    const unsigned short* aBase = sA + m16 * 776 + (quad << 3);
    const uint4* xfb = XFp + ((ull)bt << 18) + lane;   // + t*512 + kb*64 per use

    const int bb = tid >> 4, uu = tid & 15;
    const float bia_i = bi[u0 + uu], bia_f = bf_[u0 + uu];
    const float bia_o = bo[u0 + uu], bia_c = bc[u0 + uu];
    float* outp = out + (ull)((b0 + bb) * Tn) * 512 + u0 + uu;
    const float4* xg = (const float4*)x;

    if (tid < 64) sbe[tid] = be[tid];

    // -------- c-history in REGISTERS: ch[j] u32 = {slot 2j (lo16), slot 2j+1 (hi16)} --------
    unsigned ch[32];
    #pragma unroll
    for (int j = 0; j < 32; ++j) ch[j] = 0u;

    // -------- preload ALL B fragments; pinned in AGPRs (MFMA reads B from AGPR) --------
    const short8* Bg = (const short8*)BPU + (r * 4 + w) * 24 * 64 + lane;
    const short8* Be = (const short8*)BPE + w * 24 * 64 + lane;
    frag8 Bfg[24], Bfe[24];
    #pragma unroll
    for (int i = 0; i < 24; ++i) { Bfg[i].s = Bg[i << 6]; Bfe[i].s = Be[i << 6]; }

    // -------- x A-frags for t=0 --------
    frag8 xf[8];
    float4 xv[4];
    if (USEXF) {
        #pragma unroll
        for (int kb = 0; kb < 8; ++kb) xf[kb].u = xfb[kb << 6];
    } else {
        #pragma unroll
        for (int i2 = 0; i2 < 4; ++i2) {
            const int i = (i2 << 8) + tid;
            xv[i2] = xg[(((b0 + (i >> 6)) * Tn) << 6) + (i & 63)];
        }
        #pragma unroll
        for (int i2 = 0; i2 < 4; ++i2) {
            const int i = (i2 << 8) + tid;
            ushort4 o; o.x = f2bf(xv[i2].x); o.y = f2bf(xv[i2].y);
            o.z = f2bf(xv[i2].z); o.w = f2bf(xv[i2].w);
            *(ushort4*)(sA + (i >> 6) * 776 + ((i & 63) << 2)) = o;
        }
        #pragma unroll
        for (int i2 = 0; i2 < 4; ++i2) {
            const int i = (i2 << 8) + tid;
            xv[i2] = xg[(((b0 + (i >> 6)) * Tn + 1) << 6) + (i & 63)];
        }
    }

    // -------- PIPELINED POLL: issue fused tag+data round for t=0 now --------
    ull hv[16];
    {
        const ull* hp0 = hb64 + (b0 << 8) + tid;   // buffer 0; init tags = 0 = want(t=0)
        #pragma unroll
        for (int j = 0; j < 16; ++j) hv[j] = ld_agent_u64(hp0 + (j << 8));
    }
    __syncthreads();

    for (int t = 0; t < Tn; ++t) {
        // pin weight fragments in AGPRs (no remat, no per-iter copy tax)
        #pragma unroll
        for (int i = 0; i < 24; ++i) {
            asm volatile("" : "+a"(Bfg[i].f));
            asm volatile("" : "+a"(Bfe[i].f));
        }

        // -------- x-part MFMAs (h-independent); 2 independent chains per output --------
        // (the t-round issued at end of previous iteration is in flight under this)
        f32x4 ag0 = {0.f, 0.f, 0.f, 0.f}, ag1 = ag0, ae0 = ag0, ae1 = ag0;
        #pragma unroll
        for (int kb = 0; kb < 8; kb += 2) {
            const short8 a0 = USEXF ? xf[kb].s     : *(const short8*)(aBase + (kb << 5));
            const short8 a1 = USEXF ? xf[kb + 1].s : *(const short8*)(aBase + ((kb + 1) << 5));
            ag0 = __builtin_amdgcn_mfma_f32_16x16x32_bf16(a0, Bfg[kb].s,     ag0, 0, 0, 0);
            ae0 = __builtin_amdgcn_mfma_f32_16x16x32_bf16(a0, Bfe[kb].s,     ae0, 0, 0, 0);
            ag1 = __builtin_amdgcn_mfma_f32_16x16x32_bf16(a1, Bfg[kb + 1].s, ag1, 0, 0, 0);
            ae1 = __builtin_amdgcn_mfma_f32_16x16x32_bf16(a1, Bfe[kb + 1].s, ae1, 0, 0, 0);
        }

        // -------- prefetch next-step x A-frags (this step's xf consumed) --------
        if (USEXF) {
            if (t + 1 < Tn) {
                const uint4* xn = xfb + ((t + 1) << 9);
                #pragma unroll
                for (int kb = 0; kb < 8; ++kb) xf[kb].u = xn[kb << 6];
            }
        }

        // -------- detect: round already ~600cy in flight; retry-0 immediate, then sleep --
        const ull* hp = hb64 + ((t & 1) << 14) + (b0 << 8) + tid;
        {
            const unsigned want = (unsigned)t;
            int miss = 0;
            while (true) {
                bool ok = true;
                #pragma unroll
                for (int j = 0; j < 16; ++j) ok &= ((unsigned)(hv[j] >> 32) == want);
                if (__all(ok)) break;
                if (miss++) __builtin_amdgcn_s_sleep(1);
                #pragma unroll
                for (int j = 0; j < 16; ++j) hv[j] = ld_agent_u64(hp + (j << 8));
            }
        }

        // -------- h -> sA h-region (low 32 bits = 2 bf16), row j, pair col tid --------
        #pragma unroll
        for (int j = 0; j < 16; ++j)
            *(unsigned*)(sA + j * 776 + 256 + (tid << 1)) = (unsigned)hv[j];
        __syncthreads();   // A: h visible to all waves

        if (!USEXF) {
            if (t + 1 < Tn) {       // fallback: restage x_{t+1} + prefetch x_{t+2}
                #pragma unroll
                for (int i2 = 0; i2 < 4; ++i2) {
                    const int i = (i2 << 8) + tid;
                    ushort4 o; o.x = f2bf(xv[i2].x); o.y = f2bf(xv[i2].y);
                    o.z = f2bf(xv[i2].z); o.w = f2bf(xv[i2].w);
                    *(ushort4*)(sA + (i >> 6) * 776 + ((i & 63) << 2)) = o;
                }
            }
            if (t + 2 < Tn) {
                #pragma unroll
                for (int i2 = 0; i2 < 4; ++i2) {
                    const int i = (i2 << 8) + tid;
                    xv[i2] = xg[(((b0 + (i >> 6)) * Tn + t + 2) << 6) + (i & 63)];
                }
            }
        }

        // -------- h-part MFMAs (2 chains) --------
        #pragma unroll
        for (int kb = 8; kb < 24; kb += 2) {
            const short8 a0 = *(const short8*)(aBase + (kb << 5));
            const short8 a1 = *(const short8*)(aBase + ((kb + 1) << 5));
            ag0 = __builtin_amdgcn_mfma_f32_16x16x32_bf16(a0, Bfg[kb].s,     ag0, 0, 0, 0);
            ae0 = __builtin_amdgcn_mfma_f32_16x16x32_bf16(a0, Bfe[kb].s,     ae0, 0, 0, 0);
            ag1 = __builtin_amdgcn_mfma_f32_16x16x32_bf16(a1, Bfg[kb + 1].s, ag1, 0, 0, 0);
            ae1 = __builtin_amdgcn_mfma_f32_16x16x32_bf16(a1, Bfe[kb + 1].s, ae1, 0, 0, 0);
        }

        // -------- exchange: gate z (bank-swizzled) + ze into LDS --------
        #pragma unroll
        for (int i = 0; i < 4; ++i) {
            const int zrow = ((quad << 2) + i) * 16 + m16;
            zs[(zrow << 2) + ((w + (zrow >> 2)) & 3)] = ag0[i] + ag1[i];
            zel[((quad << 2) + i) * 68 + (w << 4) + m16] = ae0[i] + ae1[i];
        }
        __syncthreads();                       // C: cross-wave z/ze visible

        // -------- local softmax (NO max-subtract: |ze| <= ~3, exp safe in fp32) --------
        {
            const float* zb = zel + bb * 68;
            const int l = uu;
            const float e0 = __expf(zb[l]      + sbe[l]);
            const float e1 = __expf(zb[l + 16] + sbe[l + 16]);
            const float e2 = __expf(zb[l + 32] + sbe[l + 32]);
            const float e3 = __expf(zb[l + 48] + sbe[l + 48]);
            float ssum = (e0 + e1) + (e2 + e3);
            #pragma unroll
            for (int off = 8; off; off >>= 1) ssum += __shfl_xor(ssum, off, 16);
            const float inv = 1.0f / ssum;
            float* st = esm + bb * 68;          // row bb written+read by SAME 16-lane
            st[l]      = e0 * inv;              // group of the same wave -> no barrier
            st[l + 16] = e1 * inv;
            st[l + 32] = e2 * inv;
            st[l + 48] = e3 * inv;
        }

        // -------- gates (swizzled b32 reads) + 64-tap memory read, 4 indep fma chains --------
        const int zc4 = (tid >> 2) & 3;
        const float zi = zs[(tid << 2) + ( zc4          & 3)] + bia_i;
        const float zf = zs[(tid << 2) + ((1 + zc4) & 3)] + bia_f;
        const float zo = zs[(tid << 2) + ((2 + zc4) & 3)] + bia_o;
        const float zc = zs[(tid << 2) + ((3 + zc4) & 3)] + bia_c;
        float mcA = 0.f, mcB = 0.f, mcC = 0.f, mcD = 0.f;
        const float4* ef = (const float4*)(esm + bb * 68);
        #pragma unroll
        for (int q = 0; q < 4; ++q) {
            const float4 e4 = ef[q];
            const unsigned c0 = ch[2 * q], c1 = ch[2 * q + 1];
            mcA = fmaf(__uint_as_float(c0 << 16),         e4.x, mcA);
            mcA = fmaf(__uint_as_float(c0 & 0xFFFF0000u), e4.y, mcA);
            mcA = fmaf(__uint_as_float(c1 << 16),         e4.z, mcA);
            mcA = fmaf(__uint_as_float(c1 & 0xFFFF0000u), e4.w, mcA);
        }
        #pragma unroll
        for (int q = 4; q < 8; ++q) {
            const float4 e4 = ef[q];
            const unsigned c0 = ch[2 * q], c1 = ch[2 * q + 1];
            mcB = fmaf(__uint_as_float(c0 << 16),         e4.x, mcB);
            mcB = fmaf(__uint_as_float(c0 & 0xFFFF0000u), e4.y, mcB);
            mcB = fmaf(__uint_as_float(c1 << 16),         e4.z, mcB);
            mcB = fmaf(__uint_as_float(c1 & 0xFFFF0000u), e4.w, mcB);
        }
        #pragma unroll
        for (int q = 8; q < 12; ++q) {
            const float4 e4 = ef[q];
            const unsigned c0 = ch[2 * q], c1 = ch[2 * q + 1];
            mcC = fmaf(__uint_as_float(c0 << 16),         e4.x, mcC);
            mcC = fmaf(__uint_as_float(c0 & 0xFFFF0000u), e4.y, mcC);
            mcC = fmaf(__uint_as_float(c1 << 16),         e4.z, mcC);
            mcC = fmaf(__uint_as_float(c1 & 0xFFFF0000u), e4.w, mcC);
        }
        #pragma unroll
        for (int q = 12; q < 16; ++q) {
            const float4 e4 = ef[q];
            const unsigned c0 = ch[2 * q], c1 = ch[2 * q + 1];
            mcD = fmaf(__uint_as_float(c0 << 16),         e4.x, mcD);
            mcD = fmaf(__uint_as_float(c0 & 0xFFFF0000u), e4.y, mcD);
            mcD = fmaf(__uint_as_float(c1 << 16),         e4.z, mcD);
            mcD = fmaf(__uint_as_float(c1 & 0xFFFF0000u), e4.w, mcD);
        }
        const float mc = (mcA + mcB) + (mcC + mcD);
        const float cc = sigmoidf_(zf) * mc + sigmoidf_(zi) * tanhf_(zc);
        const float hh = sigmoidf_(zo) * tanhf_(cc);
        const float nh = __shfl_xor(hh, 1);
        if (!(tid & 1)) {                       // publish: tagged pair [t+1 | h,h]
            const ull v = ((ull)(unsigned)(t + 1) << 32)
                        | (ull)((unsigned)f2bf(hh) | ((unsigned)f2bf(nh) << 16));
            st_agent_u64(hb64 + (((t + 1) & 1) << 14) + ((b0 + bb) << 8)
                         + ((u0 + uu) >> 1), v);
        }

        // -------- EARLY ISSUE of the t+1 fused round (right after publish): the --------
        // -------- ~700cy LLC round trip overlaps out-store + ch-shift + x-MFMA  --------
        if (t + 1 < Tn) {
            const ull* hn = hb64 + (((t + 1) & 1) << 14) + (b0 << 8) + tid;
            #pragma unroll
            for (int j = 0; j < 16; ++j) hv[j] = ld_agent_u64(hn + (j << 8));
        }

        outp[t << 9] = hh;                      // out store off-path

        // -------- shift c-history regs: slot k <- slot k-1, slot0 <- c_t --------
        #pragma unroll
        for (int j = 31; j > 0; --j) ch[j] = (ch[j] << 16) | (ch[j - 1] >> 16);
        ch[0] = (ch[0] << 16) | (unsigned)f2bf(cc);
    }
}

// ---------------- init: zero tagged-h buffers, pack weights + x frags ----------------
__global__ __launch_bounds__(NTHR) void init_k(
    const float* __restrict__ x,
    const float* __restrict__ Wi, const float* __restrict__ Ui,
    const float* __restrict__ Wf, const float* __restrict__ Uf,
    const float* __restrict__ Wo, const float* __restrict__ Uo,
    const float* __restrict__ Wc, const float* __restrict__ Uc,
    const float* __restrict__ We, const float* __restrict__ Ue,
    float* __restrict__ ws, int fillxf)
{
    const int idx = blockIdx.x * NTHR + threadIdx.x;
    const int stride = gridDim.x * NTHR;
    unsigned* ctr = (unsigned*)ws;
    for (int i = idx; i < 512; i += stride) ctr[i] = 0u;
    unsigned* hbu = (unsigned*)(ws + HB_OFF);
    for (int i = idx; i < 65536; i += stride) hbu[i] = 0u;   // both tagged-h buffers = 0

    unsigned short* BPU = (unsigned short*)(ws + BP_OFF);
    unsigned short* BPE = BPU + BPU_SH;
    const float* Wg[4] = {Wi, Wf, Wo, Wc};
    const float* Ug[4] = {Ui, Uf, Uo, Uc};
    for (int g = idx; g < 196608; g += stride) {
        const int lane = g & 63, rest = g >> 6;
        const int kb = rest % 24, rest2 = rest / 24;
        const int w2 = rest2 & 3, rr = rest2 >> 2;
        const int cs = (rr << 4) + (lane & 15);
        const int kbase = (kb << 5) + ((lane >> 4) << 3);
        #pragma unroll
        for (int j = 0; j < 8; ++j) {
            const int k = kbase + j;
            const float v = (k < 256) ? Wg[w2][(k << 9) + cs]
                                      : Ug[w2][((k - 256) << 9) + cs];
            BPU[(g << 3) + j] = f2bf(v);
        }
    }
    for (int g = idx; g < 6144; g += stride) {
        const int lane = g & 63, rest = g >> 6;
        const int kb = rest % 24, w2 = rest / 24;
        const int cs = (w2 << 4) + (lane & 15);
        const int kbase = (kb << 5) + ((lane >> 4) << 3);
        #pragma unroll
        for (int j = 0; j < 8; ++j) {
            const int k = kbase + j;
            const float v = (k < 256) ? We[(k << 6) + cs] : Ue[((k - 256) << 6) + cs];
            BPE[(g << 3) + j] = f2bf(v);
        }
    }
    if (fillxf) {
        uint4* XFp = (uint4*)(ws + XF_OFF);
        for (int g = idx; g < XF_U4; g += stride) {
            const int lane = g & 63, kb = (g >> 6) & 7, t = (g >> 9) & 511, bt = g >> 18;
            const int m16 = lane & 15, quad = lane >> 4;
            const int b = (bt << 4) + m16;
            const int k0 = (kb << 5) + (quad << 3);
            const float* xr = x + (((ull)(b * Tn + t)) << 8) + k0;
            unsigned short us[8];
            #pragma unroll
            for (int j = 0; j < 8; ++j) us[j] = f2bf(xr[j]);
            uint4 o;
            o.x = (unsigned)us[0] | ((unsigned)us[1] << 16);
            o.y = (unsigned)us[2] | ((unsigned)us[3] << 16);
            o.z = (unsigned)us[4] | ((unsigned)us[5] << 16);
            o.w = (unsigned)us[6] | ((unsigned)us[7] << 16);
            XFp[g] = o;
        }
    }
}

extern "C" void kernel_launch(void* const* d_in, const int* in_sizes, int n_in,
                              void* d_out, int out_size, void* d_ws, size_t ws_size,
                              hipStream_t stream) {
    const float* x  = (const float*)d_in[0];
    const float* Wi = (const float*)d_in[1];
    const float* Ui = (const float*)d_in[2];
    const float* bi = (const float*)d_in[3];
    const float* Wf = (const float*)d_in[4];
    const float* Uf = (const float*)d_in[5];
    const float* bf = (const float*)d_in[6];
    const float* Wo = (const float*)d_in[7];
    const float* Uo = (const float*)d_in[8];
    const float* bo = (const float*)d_in[9];
    const float* Wc = (const float*)d_in[10];
    const float* Uc = (const float*)d_in[11];
    const float* bc = (const float*)d_in[12];
    const float* We = (const float*)d_in[13];
    const float* Ue = (const float*)d_in[14];
    const float* be = (const float*)d_in[15];
    float* out = (float*)d_out;
    float* ws  = (float*)d_ws;

    const int use_xf = (ws_size >= (size_t)WS_NEED_F * sizeof(float)) ? 1 : 0;

    init_k<<<512, NTHR, 0, stream>>>(x, Wi, Ui, Wf, Uf, Wo, Uo, Wc, Uc, We, Ue,
                                     ws, use_xf);

    void* args[] = { &x, &bi, &bf, &bo, &bc, &be, &out, &ws };
    const void* kfun = use_xf ? (const void*)xlstm_k<true>
                              : (const void*)xlstm_k<false>;
    hipError_t e = hipLaunchCooperativeKernel(kfun, dim3(GRID), dim3(NTHR),
                                              args, 0, stream);
    if (e != hipSuccess) {
        (void)hipGetLastError();   // 128 wgs co-reside trivially; plain launch fallback
        if (use_xf)
            xlstm_k<true><<<GRID, NTHR, 0, stream>>>(x, bi, bf, bo, bc, be, out, ws);
        else
            xlstm_k<false><<<GRID, NTHR, 0, stream>>>(x, bi, bf, bo, bc, be, out, ws);
    }
}

// Round 9
// 1663.488 us; speedup vs baseline: 1.2998x; 1.2998x over previous
//
#include <hip/hip_runtime.h>

// Problem constants
#define Bn   64
#define Tn   512
#define Dn   256
#define Un   512
#define Mn   64
#define NTHR 256
#define GRID 128                  // 4 b-tiles x 32 u-tiles (e fused into every wg)

// ws layout (float index):
//   [0..127]     (zeroed; reserved)
//   HB_OFF  (65536 f)  hbuf as u64[2][64][256]: [tag32 | 2x bf16 h], double buffer
//   BP_OFF  ushort area: BPU (1572864 sh) gate weights, BPE (49152 sh) e weights
//   XF_OFF  uint4 area: x pre-converted to bf16 MFMA A-frag layout
//           XF[((bt*512 + t)*8 + kb)*64 + lane] = 8 bf16 = x[bt*16+(lane&15)][k=kb*32+(lane>>4)*8 + 0..7]
#define HB_OFF    5120
#define BP_OFF    70656
#define BPU_SH    1572864
#define BPE_SH    49152
#define XF_OFF    881664          // floats = BP_OFF + (BPU_SH+BPE_SH)/2
#define XF_U4     1048576         // 4*512*8*64 uint4 entries (16 MB)
#define WS_NEED_F (XF_OFF + XF_U4*4)

typedef __attribute__((ext_vector_type(8))) short short8;
typedef __attribute__((ext_vector_type(4))) float f32x4;
typedef unsigned long long ull;

union frag8 { short8 s; f32x4 f; uint4 u; };   // views for asm keep-alive / loads

__device__ __forceinline__ float sigmoidf_(float v) { return 1.0f / (1.0f + __expf(-v)); }
__device__ __forceinline__ float tanhf_(float v) {   // hw-exp tanh; |v| small here
    const float e = __expf(2.0f * v);
    return (e - 1.0f) / (e + 1.0f);
}

__device__ __forceinline__ unsigned short f2bf(float f) {   // RNE fp32 -> bf16
    unsigned u = __float_as_uint(f);
    return (unsigned short)((u + 0x7FFFu + ((u >> 16) & 1u)) >> 16);
}

__device__ __forceinline__ void st_agent_u64(ull* p, ull v) {
    __hip_atomic_store(p, v, __ATOMIC_RELAXED, __HIP_MEMORY_SCOPE_AGENT);
}
__device__ __forceinline__ ull ld_agent_u64(const void* p) {
    return __hip_atomic_load((const ull*)p, __ATOMIC_RELAXED, __HIP_MEMORY_SCOPE_AGENT);
}

template<bool USEXF>
__global__ __launch_bounds__(NTHR, 1) void xlstm_k(
    const float* __restrict__ x,
    const float* __restrict__ bi, const float* __restrict__ bf_,
    const float* __restrict__ bo, const float* __restrict__ bc,
    const float* __restrict__ be,
    float* __restrict__ out, float* __restrict__ ws)
{
    __shared__ unsigned short sA[16 * 776];  // 24.8 KB xh tile bf16 (row pad 8); x region only used by fallback
    __shared__ float zs[1024];               // gate z, swizzled: zs[row*4 + ((gate + row>>2)&3)]
    __shared__ float zel[16 * 68];           // ze [16 b][64 e] (pad 68)
    __shared__ float esm[16 * 68];           // e [16 b][64], DIRECT slot order
    __shared__ float sbe[64];                // be staged

    ull* hb64 = (ull*)(ws + HB_OFF);
    const unsigned short* BPU = (const unsigned short*)(ws + BP_OFF);
    const unsigned short* BPE = BPU + BPU_SH;
    const uint4* XFp = (const uint4*)(ws + XF_OFF);

    const int tid = threadIdx.x, wg = blockIdx.x;
    // XCD co-location (ISOLATED test): WG i -> XCD i%8 (measured round-robin).
    // bt=(wg&7)>>1 puts each b-tile's 32 communicating WGs on exactly 2 XCDs.
    // Addresses unchanged; only request sources move. Everything else == R7 champion.
    const int bt = (wg & 7) >> 1;
    const int r  = ((wg >> 3) << 1) | (wg & 1);
    const int b0 = bt << 4, u0 = r << 4;
    const int lane = tid & 63, w = tid >> 6;       // wave = gate index
    const int quad = lane >> 4, m16 = lane & 15;
    const unsigned short* aBase = sA + m16 * 776 + (quad << 3);
    const uint4* xfb = XFp + ((ull)bt << 18) + lane;   // + t*512 + kb*64 per use

    const int bb = tid >> 4, uu = tid & 15;
    const float bia_i = bi[u0 + uu], bia_f = bf_[u0 + uu];
    const float bia_o = bo[u0 + uu], bia_c = bc[u0 + uu];
    float* outp = out + (ull)((b0 + bb) * Tn) * 512 + u0 + uu;
    const float4* xg = (const float4*)x;

    if (tid < 64) sbe[tid] = be[tid];

    // -------- c-history in REGISTERS: ch[j] u32 = {slot 2j (lo16), slot 2j+1 (hi16)} --------
    unsigned ch[32];
    #pragma unroll
    for (int j = 0; j < 32; ++j) ch[j] = 0u;

    // -------- preload ALL B fragments; pinned in AGPRs (MFMA reads B from AGPR) --------
    const short8* Bg = (const short8*)BPU + (r * 4 + w) * 24 * 64 + lane;
    const short8* Be = (const short8*)BPE + w * 24 * 64 + lane;
    frag8 Bfg[24], Bfe[24];
    #pragma unroll
    for (int i = 0; i < 24; ++i) { Bfg[i].s = Bg[i << 6]; Bfe[i].s = Be[i << 6]; }

    // -------- x A-frags for t=0 --------
    frag8 xf[8];
    float4 xv[4];
    if (USEXF) {
        #pragma unroll
        for (int kb = 0; kb < 8; ++kb) xf[kb].u = xfb[kb << 6];
    } else {
        #pragma unroll
        for (int i2 = 0; i2 < 4; ++i2) {
            const int i = (i2 << 8) + tid;
            xv[i2] = xg[(((b0 + (i >> 6)) * Tn) << 6) + (i & 63)];
        }
        #pragma unroll
        for (int i2 = 0; i2 < 4; ++i2) {
            const int i = (i2 << 8) + tid;
            ushort4 o; o.x = f2bf(xv[i2].x); o.y = f2bf(xv[i2].y);
            o.z = f2bf(xv[i2].z); o.w = f2bf(xv[i2].w);
            *(ushort4*)(sA + (i >> 6) * 776 + ((i & 63) << 2)) = o;
        }
        #pragma unroll
        for (int i2 = 0; i2 < 4; ++i2) {
            const int i = (i2 << 8) + tid;
            xv[i2] = xg[(((b0 + (i >> 6)) * Tn + 1) << 6) + (i & 63)];
        }
    }
    __syncthreads();

    for (int t = 0; t < Tn; ++t) {
        // pin weight fragments in AGPRs (no remat, no per-iter copy tax)
        #pragma unroll
        for (int i = 0; i < 24; ++i) {
            asm volatile("" : "+a"(Bfg[i].f));
            asm volatile("" : "+a"(Bfe[i].f));
        }

        // -------- x-part MFMAs (h-independent); 2 independent chains per output --------
        f32x4 ag0 = {0.f, 0.f, 0.f, 0.f}, ag1 = ag0, ae0 = ag0, ae1 = ag0;
        #pragma unroll
        for (int kb = 0; kb < 8; kb += 2) {
            const short8 a0 = USEXF ? xf[kb].s     : *(const short8*)(aBase + (kb << 5));
            const short8 a1 = USEXF ? xf[kb + 1].s : *(const short8*)(aBase + ((kb + 1) << 5));
            ag0 = __builtin_amdgcn_mfma_f32_16x16x32_bf16(a0, Bfg[kb].s,     ag0, 0, 0, 0);
            ae0 = __builtin_amdgcn_mfma_f32_16x16x32_bf16(a0, Bfe[kb].s,     ae0, 0, 0, 0);
            ag1 = __builtin_amdgcn_mfma_f32_16x16x32_bf16(a1, Bfg[kb + 1].s, ag1, 0, 0, 0);
            ae1 = __builtin_amdgcn_mfma_f32_16x16x32_bf16(a1, Bfe[kb + 1].s, ae1, 0, 0, 0);
        }

        // -------- prefetch next-step x A-frags (this step's xf consumed) --------
        if (USEXF) {
            if (t + 1 < Tn) {
                const uint4* xn = xfb + ((t + 1) << 9);
                #pragma unroll
                for (int kb = 0; kb < 8; ++kb) xf[kb].u = xn[kb << 6];
            }
        }

        // -------- FUSED tag+data poll: late issue; retry-0 immediate, then sleep --------
        const ull* hp = hb64 + ((t & 1) << 14) + (b0 << 8) + tid;
        ull hv[16];
        #pragma unroll
        for (int j = 0; j < 16; ++j) hv[j] = ld_agent_u64(hp + (j << 8));
        {
            const unsigned want = (unsigned)t;
            int miss = 0;
            while (true) {
                bool ok = true;
                #pragma unroll
                for (int j = 0; j < 16; ++j) ok &= ((unsigned)(hv[j] >> 32) == want);
                if (__all(ok)) break;
                if (miss++) __builtin_amdgcn_s_sleep(1);
                #pragma unroll
                for (int j = 0; j < 16; ++j) hv[j] = ld_agent_u64(hp + (j << 8));
            }
        }

        // -------- h -> sA h-region (low 32 bits = 2 bf16), row j, pair col tid --------
        #pragma unroll
        for (int j = 0; j < 16; ++j)
            *(unsigned*)(sA + j * 776 + 256 + (tid << 1)) = (unsigned)hv[j];
        __syncthreads();   // A: h visible to all waves

        if (!USEXF) {
            if (t + 1 < Tn) {       // fallback: restage x_{t+1} + prefetch x_{t+2}
                #pragma unroll
                for (int i2 = 0; i2 < 4; ++i2) {
                    const int i = (i2 << 8) + tid;
                    ushort4 o; o.x = f2bf(xv[i2].x); o.y = f2bf(xv[i2].y);
                    o.z = f2bf(xv[i2].z); o.w = f2bf(xv[i2].w);
                    *(ushort4*)(sA + (i >> 6) * 776 + ((i & 63) << 2)) = o;
                }
            }
            if (t + 2 < Tn) {
                #pragma unroll
                for (int i2 = 0; i2 < 4; ++i2) {
                    const int i = (i2 << 8) + tid;
                    xv[i2] = xg[(((b0 + (i >> 6)) * Tn + t + 2) << 6) + (i & 63)];
                }
            }
        }

        // -------- h-part MFMAs (2 chains) --------
        #pragma unroll
        for (int kb = 8; kb < 24; kb += 2) {
            const short8 a0 = *(const short8*)(aBase + (kb << 5));
            const short8 a1 = *(const short8*)(aBase + ((kb + 1) << 5));
            ag0 = __builtin_amdgcn_mfma_f32_16x16x32_bf16(a0, Bfg[kb].s,     ag0, 0, 0, 0);
            ae0 = __builtin_amdgcn_mfma_f32_16x16x32_bf16(a0, Bfe[kb].s,     ae0, 0, 0, 0);
            ag1 = __builtin_amdgcn_mfma_f32_16x16x32_bf16(a1, Bfg[kb + 1].s, ag1, 0, 0, 0);
            ae1 = __builtin_amdgcn_mfma_f32_16x16x32_bf16(a1, Bfe[kb + 1].s, ae1, 0, 0, 0);
        }

        // -------- exchange: gate z (bank-swizzled) + ze into LDS --------
        #pragma unroll
        for (int i = 0; i < 4; ++i) {
            const int zrow = ((quad << 2) + i) * 16 + m16;
            zs[(zrow << 2) + ((w + (zrow >> 2)) & 3)] = ag0[i] + ag1[i];
            zel[((quad << 2) + i) * 68 + (w << 4) + m16] = ae0[i] + ae1[i];
        }
        __syncthreads();                       // C: cross-wave z/ze visible

        // -------- local softmax (NO max-subtract: |ze| <= ~3, exp safe in fp32) --------
        {
            const float* zb = zel + bb * 68;
            const int l = uu;
            const float e0 = __expf(zb[l]      + sbe[l]);
            const float e1 = __expf(zb[l + 16] + sbe[l + 16]);
            const float e2 = __expf(zb[l + 32] + sbe[l + 32]);
            const float e3 = __expf(zb[l + 48] + sbe[l + 48]);
            float ssum = (e0 + e1) + (e2 + e3);
            #pragma unroll
            for (int off = 8; off; off >>= 1) ssum += __shfl_xor(ssum, off, 16);
            const float inv = 1.0f / ssum;
            float* st = esm + bb * 68;          // row bb written+read by SAME 16-lane
            st[l]      = e0 * inv;              // group of the same wave -> no barrier
            st[l + 16] = e1 * inv;
            st[l + 32] = e2 * inv;
            st[l + 48] = e3 * inv;
        }

        // -------- gates (swizzled b32 reads) + 64-tap memory read, 4 indep fma chains --------
        const int zc4 = (tid >> 2) & 3;
        const float zi = zs[(tid << 2) + ( zc4          & 3)] + bia_i;
        const float zf = zs[(tid << 2) + ((1 + zc4) & 3)] + bia_f;
        const float zo = zs[(tid << 2) + ((2 + zc4) & 3)] + bia_o;
        const float zc = zs[(tid << 2) + ((3 + zc4) & 3)] + bia_c;
        float mcA = 0.f, mcB = 0.f, mcC = 0.f, mcD = 0.f;
        const float4* ef = (const float4*)(esm + bb * 68);
        #pragma unroll
        for (int q = 0; q < 4; ++q) {
            const float4 e4 = ef[q];
            const unsigned c0 = ch[2 * q], c1 = ch[2 * q + 1];
            mcA = fmaf(__uint_as_float(c0 << 16),         e4.x, mcA);
            mcA = fmaf(__uint_as_float(c0 & 0xFFFF0000u), e4.y, mcA);
            mcA = fmaf(__uint_as_float(c1 << 16),         e4.z, mcA);
            mcA = fmaf(__uint_as_float(c1 & 0xFFFF0000u), e4.w, mcA);
        }
        #pragma unroll
        for (int q = 4; q < 8; ++q) {
            const float4 e4 = ef[q];
            const unsigned c0 = ch[2 * q], c1 = ch[2 * q + 1];
            mcB = fmaf(__uint_as_float(c0 << 16),         e4.x, mcB);
            mcB = fmaf(__uint_as_float(c0 & 0xFFFF0000u), e4.y, mcB);
            mcB = fmaf(__uint_as_float(c1 << 16),         e4.z, mcB);
            mcB = fmaf(__uint_as_float(c1 & 0xFFFF0000u), e4.w, mcB);
        }
        #pragma unroll
        for (int q = 8; q < 12; ++q) {
            const float4 e4 = ef[q];
            const unsigned c0 = ch[2 * q], c1 = ch[2 * q + 1];
            mcC = fmaf(__uint_as_float(c0 << 16),         e4.x, mcC);
            mcC = fmaf(__uint_as_float(c0 & 0xFFFF0000u), e4.y, mcC);
            mcC = fmaf(__uint_as_float(c1 << 16),         e4.z, mcC);
            mcC = fmaf(__uint_as_float(c1 & 0xFFFF0000u), e4.w, mcC);
        }
        #pragma unroll
        for (int q = 12; q < 16; ++q) {
            const float4 e4 = ef[q];
            const unsigned c0 = ch[2 * q], c1 = ch[2 * q + 1];
            mcD = fmaf(__uint_as_float(c0 << 16),         e4.x, mcD);
            mcD = fmaf(__uint_as_float(c0 & 0xFFFF0000u), e4.y, mcD);
            mcD = fmaf(__uint_as_float(c1 << 16),         e4.z, mcD);
            mcD = fmaf(__uint_as_float(c1 & 0xFFFF0000u), e4.w, mcD);
        }
        const float mc = (mcA + mcB) + (mcC + mcD);
        const float cc = sigmoidf_(zf) * mc + sigmoidf_(zi) * tanhf_(zc);
        const float hh = sigmoidf_(zo) * tanhf_(cc);
        const float nh = __shfl_xor(hh, 1);
        if (!(tid & 1)) {                       // publish: tagged pair [t+1 | h,h]
            const ull v = ((ull)(unsigned)(t + 1) << 32)
                        | (ull)((unsigned)f2bf(hh) | ((unsigned)f2bf(nh) << 16));
            st_agent_u64(hb64 + (((t + 1) & 1) << 14) + ((b0 + bb) << 8)
                         + ((u0 + uu) >> 1), v);
        }
        outp[t << 9] = hh;                      // out store off-path

        // -------- shift c-history regs: slot k <- slot k-1, slot0 <- c_t --------
        #pragma unroll
        for (int j = 31; j > 0; --j) ch[j] = (ch[j] << 16) | (ch[j - 1] >> 16);
        ch[0] = (ch[0] << 16) | (unsigned)f2bf(cc);
    }
}

// ---------------- init: zero tagged-h buffers, pack weights + x frags ----------------
__global__ __launch_bounds__(NTHR) void init_k(
    const float* __restrict__ x,
    const float* __restrict__ Wi, const float* __restrict__ Ui,
    const float* __restrict__ Wf, const float* __restrict__ Uf,
    const float* __restrict__ Wo, const float* __restrict__ Uo,
    const float* __restrict__ Wc, const float* __restrict__ Uc,
    const float* __restrict__ We, const float* __restrict__ Ue,
    float* __restrict__ ws, int fillxf)
{
    const int idx = blockIdx.x * NTHR + threadIdx.x;
    const int stride = gridDim.x * NTHR;
    unsigned* ctr = (unsigned*)ws;
    for (int i = idx; i < 512; i += stride) ctr[i] = 0u;
    unsigned* hbu = (unsigned*)(ws + HB_OFF);
    for (int i = idx; i < 65536; i += stride) hbu[i] = 0u;   // both tagged-h buffers = 0

    unsigned short* BPU = (unsigned short*)(ws + BP_OFF);
    unsigned short* BPE = BPU + BPU_SH;
    const float* Wg[4] = {Wi, Wf, Wo, Wc};
    const float* Ug[4] = {Ui, Uf, Uo, Uc};
    for (int g = idx; g < 196608; g += stride) {
        const int lane = g & 63, rest = g >> 6;
        const int kb = rest % 24, rest2 = rest / 24;
        const int w2 = rest2 & 3, rr = rest2 >> 2;
        const int cs = (rr << 4) + (lane & 15);
        const int kbase = (kb << 5) + ((lane >> 4) << 3);
        #pragma unroll
        for (int j = 0; j < 8; ++j) {
            const int k = kbase + j;
            const float v = (k < 256) ? Wg[w2][(k << 9) + cs]
                                      : Ug[w2][((k - 256) << 9) + cs];
            BPU[(g << 3) + j] = f2bf(v);
        }
    }
    for (int g = idx; g < 6144; g += stride) {
        const int lane = g & 63, rest = g >> 6;
        const int kb = rest % 24, w2 = rest / 24;
        const int cs = (w2 << 4) + (lane & 15);
        const int kbase = (kb << 5) + ((lane >> 4) << 3);
        #pragma unroll
        for (int j = 0; j < 8; ++j) {
            const int k = kbase + j;
            const float v = (k < 256) ? We[(k << 6) + cs] : Ue[((k - 256) << 6) + cs];
            BPE[(g << 3) + j] = f2bf(v);
        }
    }
    if (fillxf) {
        uint4* XFp = (uint4*)(ws + XF_OFF);
        for (int g = idx; g < XF_U4; g += stride) {
            const int lane = g & 63, kb = (g >> 6) & 7, t = (g >> 9) & 511, bt = g >> 18;
            const int m16 = lane & 15, quad = lane >> 4;
            const int b = (bt << 4) + m16;
            const int k0 = (kb << 5) + (quad << 3);
            const float* xr = x + (((ull)(b * Tn + t)) << 8) + k0;
            unsigned short us[8];
            #pragma unroll
            for (int j = 0; j < 8; ++j) us[j] = f2bf(xr[j]);
            uint4 o;
            o.x = (unsigned)us[0] | ((unsigned)us[1] << 16);
            o.y = (unsigned)us[2] | ((unsigned)us[3] << 16);
            o.z = (unsigned)us[4] | ((unsigned)us[5] << 16);
            o.w = (unsigned)us[6] | ((unsigned)us[7] << 16);
            XFp[g] = o;
        }
    }
}

extern "C" void kernel_launch(void* const* d_in, const int* in_sizes, int n_in,
                              void* d_out, int out_size, void* d_ws, size_t ws_size,
                              hipStream_t stream) {
    const float* x  = (const float*)d_in[0];
    const float* Wi = (const float*)d_in[1];
    const float* Ui = (const float*)d_in[2];
    const float* bi = (const float*)d_in[3];
    const float* Wf = (const float*)d_in[4];
    const float* Uf = (const float*)d_in[5];
    const float* bf = (const float*)d_in[6];
    const float* Wo = (const float*)d_in[7];
    const float* Uo = (const float*)d_in[8];
    const float* bo = (const float*)d_in[9];
    const float* Wc = (const float*)d_in[10];
    const float* Uc = (const float*)d_in[11];
    const float* bc = (const float*)d_in[12];
    const float* We = (const float*)d_in[13];
    const float* Ue = (const float*)d_in[14];
    const float* be = (const float*)d_in[15];
    float* out = (float*)d_out;
    float* ws  = (float*)d_ws;

    const int use_xf = (ws_size >= (size_t)WS_NEED_F * sizeof(float)) ? 1 : 0;

    init_k<<<512, NTHR, 0, stream>>>(x, Wi, Ui, Wf, Uf, Wo, Uo, Wc, Uc, We, Ue,
                                     ws, use_xf);

    void* args[] = { &x, &bi, &bf, &bo, &bc, &be, &out, &ws };
    const void* kfun = use_xf ? (const void*)xlstm_k<true>
                              : (const void*)xlstm_k<false>;
    hipError_t e = hipLaunchCooperativeKernel(kfun, dim3(GRID), dim3(NTHR),
                                              args, 0, stream);
    if (e != hipSuccess) {
        (void)hipGetLastError();   // 128 wgs co-reside trivially; plain launch fallback
        if (use_xf)
            xlstm_k<true><<<GRID, NTHR, 0, stream>>>(x, bi, bf, bo, bc, be, out, ws);
        else
            xlstm_k<false><<<GRID, NTHR, 0, stream>>>(x, bi, bf, bo, bc, be, out, ws);
    }
}